// Round 1
// baseline (22905.588 us; speedup 1.0000x reference)
//
#include <hip/hip_runtime.h>
#include <hip/hip_fp16.h>

#define LOG2E 1.44269504088896340736f
#define BB 256
#define TT 128
#define SS 128
#define UU 256

// ---------------- parameter precompute ----------------
// recurrent: a2 = -sigma*log2e, b2 = sigma*mu*log2e  (sigmoid(z)=1/(1+2^(a2*v+b2)))
//            ws = softplus(w)*erev   (num += ws*s, den += |ws|*s)
// sensory:  same in f32 (only ~3% of work)
// per-unit: cmt = softplus(cm)*ODE_UNFOLDS; gnum = gl*vleak; cden = cmt+gl+EPS_DIV
__global__ __launch_bounds__(256) void prep_kernel(
    const float* __restrict__ sensory_w, const float* __restrict__ sensory_mu,
    const float* __restrict__ sensory_sigma, const float* __restrict__ sensory_erev,
    const float* __restrict__ w, const float* __restrict__ mu,
    const float* __restrict__ sigma, const float* __restrict__ erev,
    const float* __restrict__ gleak, const float* __restrict__ vleak,
    const float* __restrict__ cm,
    __half2* __restrict__ a2b2, __half* __restrict__ wsh,
    float* __restrict__ sa, float* __restrict__ sb, float* __restrict__ sws,
    float* __restrict__ cmt, float* __restrict__ gnum, float* __restrict__ cden)
{
    int e = blockIdx.x * 256 + threadIdx.x;
    if (e < UU * UU) {
        float sg = sigma[e], m = mu[e], wv = w[e], er = erev[e];
        a2b2[e] = __floats2half2_rn(-sg * LOG2E, sg * m * LOG2E);
        wsh[e] = __float2half_rn(log1pf(expf(wv)) * er);
    }
    if (e < SS * UU) {
        float sg = sensory_sigma[e], m = sensory_mu[e], wv = sensory_w[e], er = sensory_erev[e];
        sa[e] = -sg * LOG2E;
        sb[e] = sg * m * LOG2E;
        sws[e] = log1pf(expf(wv)) * er;
    }
    if (e < UU) {
        float gl = log1pf(expf(gleak[e]));
        float c = log1pf(expf(cm[e])) * 6.0f;   // ODE_UNFOLDS=6, ts=1
        cmt[e] = c;
        gnum[e] = gl * vleak[e];
        cden[e] = c + gl + 1e-8f;
    }
}

// ---------------- main sequential kernel: 1 block = 1 batch element ----------------
// 1024 threads: j = tid&255 (post-unit), q = tid>>8 (i-range quarter).
__global__ __launch_bounds__(1024, 4) void ltc_kernel(
    const float* __restrict__ x,
    const float* __restrict__ input_w, const float* __restrict__ input_b,
    const float* __restrict__ halt_w, const float* __restrict__ halt_b,
    const float* __restrict__ out_w, const float* __restrict__ out_b,
    const __half2* __restrict__ a2b2, const __half* __restrict__ wsh,
    const float* __restrict__ sa, const float* __restrict__ sb, const float* __restrict__ sws,
    const float* __restrict__ cmt, const float* __restrict__ gnum, const float* __restrict__ cden,
    float* __restrict__ readout, float* __restrict__ h_state, float* __restrict__ ponder_out)
{
    const int b = blockIdx.x;
    const int tid = threadIdx.x;
    const int j = tid & (UU - 1);
    const int q = tid >> 8;

    __shared__ __align__(16) float v_sh[UU];
    __shared__ __align__(16) float xin_sh[SS];
    __shared__ float np_sh[4][UU];
    __shared__ float dp_sh[4][UU];
    __shared__ float red_sh[4];
    __shared__ float sc_weight;
    __shared__ int sc_halt;

    float p_cmt = 0.f, p_hw = 0.f, p_ow = 0.f, p_ob = 0.f, p_gnum = 0.f, p_cden = 0.f;
    if (tid < UU) {
        p_cmt = cmt[j]; p_hw = halt_w[j]; p_ow = out_w[j]; p_ob = out_b[j];
        p_gnum = gnum[j]; p_cden = cden[j];
        v_sh[j] = 0.0f;
    }
    float iw = 0.f, ibv = 0.f;
    if (tid < SS) { iw = input_w[tid]; ibv = input_b[tid]; }
    const float hb = halt_b[0];

    float acc = 0.0f;          // tid<256: per-unit ACT accumulator (becomes next state)
    float pond = 0.0f;         // tid0
    float halt_sum = 0.0f, rem = 0.0f;  // tid0

    const int ib0 = q * 64;    // recurrent pre-unit range
    const int sb0 = q * 32;    // sensory pre-unit range

    __syncthreads();

    for (int t = 0; t < TT; ++t) {
        // ---- input mapping into LDS ----
        if (tid < SS) {
            float xv = x[((size_t)b * TT + t) * SS + tid];
            xin_sh[tid] = fmaf(xv, iw, ibv);
        }
        __syncthreads();

        // ---- sensory pass (depends only on xin; once per t) ----
        {
            float rn = 0.f, rd = 0.f;
            #pragma unroll 2
            for (int ii = 0; ii < 32; ii += 4) {
                float4 vv = *(const float4*)&xin_sh[sb0 + ii];
                float vk[4] = {vv.x, vv.y, vv.z, vv.w};
                #pragma unroll
                for (int k = 0; k < 4; ++k) {
                    int idx = (sb0 + ii + k) * UU + j;
                    float z = fmaf(sa[idx], vk[k], sb[idx]);
                    float e = __builtin_amdgcn_exp2f(z);
                    float s = __builtin_amdgcn_rcpf(1.0f + e);
                    float wv = sws[idx];
                    rn = fmaf(wv, s, rn);
                    rd = fmaf(fabsf(wv), s, rd);
                }
            }
            np_sh[q][j] = rn;
            dp_sh[q][j] = rd;
        }
        __syncthreads();

        float basen = 0.f, based = 0.f;
        if (tid < UU) {
            basen = np_sh[0][j] + np_sh[1][j] + np_sh[2][j] + np_sh[3][j] + p_gnum;
            based = dp_sh[0][j] + dp_sh[1][j] + dp_sh[2][j] + dp_sh[3][j] + p_cden;
        }
        acc = 0.0f;
        halt_sum = 0.0f; rem = 0.0f;
        int n_updates = 0;
        __syncthreads();   // np/dp consumed before unfold-1 rewrites them

        // ---- ACT loop with early exit (halted iterations contribute nothing) ----
        for (int n = 0; n < 10; ++n) {
            #pragma unroll 1
            for (int u = 0; u < 6; ++u) {
                float rn = 0.f, rd = 0.f;
                #pragma unroll 4
                for (int ii = 0; ii < 64; ii += 4) {
                    float4 vv = *(const float4*)&v_sh[ib0 + ii];
                    float vk[4] = {vv.x, vv.y, vv.z, vv.w};
                    #pragma unroll
                    for (int k = 0; k < 4; ++k) {
                        int idx = (ib0 + ii + k) * UU + j;
                        float2 ab = __half22float2(a2b2[idx]);
                        float z = fmaf(ab.x, vk[k], ab.y);
                        float e = __builtin_amdgcn_exp2f(z);
                        float s = __builtin_amdgcn_rcpf(1.0f + e);
                        float wv = __half2float(wsh[idx]);
                        rn = fmaf(wv, s, rn);
                        rd = fmaf(fabsf(wv), s, rd);
                    }
                }
                np_sh[q][j] = rn;
                dp_sh[q][j] = rd;
                __syncthreads();
                if (tid < UU) {
                    float tn = np_sh[0][j] + np_sh[1][j] + np_sh[2][j] + np_sh[3][j] + basen;
                    float td = dp_sh[0][j] + dp_sh[1][j] + dp_sh[2][j] + dp_sh[3][j] + based;
                    v_sh[j] = fmaf(p_cmt, v_sh[j], tn) / td;
                }
                __syncthreads();
            }

            // halting probability p = sigmoid(v . halt_w + halt_b)
            float hpart = (tid < UU) ? v_sh[j] * p_hw : 0.0f;
            #pragma unroll
            for (int off = 32; off > 0; off >>= 1)
                hpart += __shfl_down(hpart, off, 64);
            if (tid < UU && (tid & 63) == 0) red_sh[tid >> 6] = hpart;
            __syncthreads();
            if (tid == 0) {
                float dot = red_sh[0] + red_sh[1] + red_sh[2] + red_sh[3] + hb;
                float pr = __builtin_amdgcn_rcpf(1.0f + __builtin_amdgcn_exp2f(-dot * LOG2E));
                float new_sum = halt_sum + pr;
                int halting = (n == 9) || (new_sum >= 0.99f);
                float r = 1.0f - halt_sum;
                sc_weight = halting ? r : pr;
                sc_halt = halting;
                halt_sum = new_sum;
                if (halting) rem += r;
            }
            __syncthreads();
            float wgt = sc_weight;
            int halted = sc_halt;
            if (tid < UU) acc = fmaf(wgt, v_sh[j], acc);
            ++n_updates;
            if (halted) break;
        }

        // ---- t epilogue: new_state = acc ----
        if (tid == 0) pond += (float)n_updates + rem;
        if (tid < UU) {
            readout[((size_t)b * TT + t) * UU + j] = fmaf(acc, p_ow, p_ob);
            v_sh[j] = acc;   // visibility to other threads ordered by next t's barrier
        }
    }

    if (tid < UU) h_state[(size_t)b * UU + j] = acc;
    if (tid == 0) atomicAdd(ponder_out, pond * (1.0f / BB));
}

// ---------------- launch ----------------
extern "C" void kernel_launch(void* const* d_in, const int* in_sizes, int n_in,
                              void* d_out, int out_size, void* d_ws, size_t ws_size,
                              hipStream_t stream)
{
    const float* x             = (const float*)d_in[0];
    const float* input_w       = (const float*)d_in[1];
    const float* input_b       = (const float*)d_in[2];
    const float* sensory_w     = (const float*)d_in[3];
    const float* sensory_mu    = (const float*)d_in[4];
    const float* sensory_sigma = (const float*)d_in[5];
    const float* sensory_erev  = (const float*)d_in[6];
    const float* w             = (const float*)d_in[7];
    const float* mu            = (const float*)d_in[8];
    const float* sigma         = (const float*)d_in[9];
    const float* erev          = (const float*)d_in[10];
    const float* gleak         = (const float*)d_in[11];
    const float* vleak         = (const float*)d_in[12];
    const float* cm            = (const float*)d_in[13];
    const float* output_w      = (const float*)d_in[14];
    const float* output_b      = (const float*)d_in[15];
    const float* halt_w        = (const float*)d_in[16];
    const float* halt_b        = (const float*)d_in[17];

    float* readout = (float*)d_out;
    float* h_state = readout + (size_t)BB * TT * UU;
    float* ponder  = h_state + (size_t)BB * UU;

    char* wsb = (char*)d_ws;
    __half2* a2b2 = (__half2*)wsb;  wsb += (size_t)UU * UU * sizeof(__half2);
    __half*  wsh  = (__half*)wsb;   wsb += (size_t)UU * UU * sizeof(__half);
    float* sa   = (float*)wsb;      wsb += (size_t)SS * UU * 4;
    float* sb_  = (float*)wsb;      wsb += (size_t)SS * UU * 4;
    float* sws  = (float*)wsb;      wsb += (size_t)SS * UU * 4;
    float* cmt  = (float*)wsb;      wsb += (size_t)UU * 4;
    float* gnum = (float*)wsb;      wsb += (size_t)UU * 4;
    float* cden = (float*)wsb;      wsb += (size_t)UU * 4;

    hipMemsetAsync(ponder, 0, sizeof(float), stream);
    prep_kernel<<<(UU * UU) / 256, 256, 0, stream>>>(
        sensory_w, sensory_mu, sensory_sigma, sensory_erev,
        w, mu, sigma, erev, gleak, vleak, cm,
        a2b2, wsh, sa, sb_, sws, cmt, gnum, cden);
    ltc_kernel<<<BB, 1024, 0, stream>>>(
        x, input_w, input_b, halt_w, halt_b, output_w, output_b,
        a2b2, wsh, sa, sb_, sws, cmt, gnum, cden,
        readout, h_state, ponder);
}